// Round 10
// baseline (600.572 us; speedup 1.0000x reference)
//
#include <hip/hip_runtime.h>
#include <math.h>

#define BB 8
#define DD 128
#define HWD 65536    // 256*256
#define NBLK 2048    // 524288 px / 256 px per block

__device__ __forceinline__ float warp_red_sum(float v) {
#pragma unroll
    for (int off = 32; off > 0; off >>= 1) v += __shfl_down(v, off, 64);
    return v;
}

// 256 threads = 4 waves. Block = 256 pixels x 128 channels.
// Wave w owns channels [32w,32w+32); lane owns 4 px (float4 loads).
// Explicit two-loop: pass 1 accumulates norms (8 live regs), pass 2 re-loads
// the block-local 256 KB tile (L2/L3-hot) for the exp sums (12 live regs).
// Nothing held across the barrier -> nothing to spill or rematerialize.
__global__ __launch_bounds__(256, 4)
void pixel_dino_main(const float* __restrict__ s_feats,
                     const float* __restrict__ t_feats,
                     const float* __restrict__ center,
                     const void*  __restrict__ mask,
                     const float* __restrict__ orig_x,
                     float* __restrict__ ws) {
    const float TAU_S_INV = 10.0f, TAU_T_INV = 25.0f, EPSN = 1e-12f;
    const int tid  = threadIdx.x;
    const int lane = tid & 63;
    const int wave = tid >> 6;                      // 0..3
    const int b    = blockIdx.x >> 8;               // 256 blocks per image
    const int pix0 = (blockIdx.x & 255) << 8;       // 256 px per block
    const size_t base = (size_t)b * (DD * HWD) + pix0;
    const float* sp = s_feats + base + (lane << 2);
    const float* tp = t_feats + base + (lane << 2);
    const int c0 = wave << 5;

    __shared__ float red[3][4][256];                // 12 KB
    __shared__ float tot[3][256];                   // 3 KB
    __shared__ float fin[2][4];

    // --- self-detect mask dtype from first 1 KB (per-wave ballots, ~free) ---
    // flag: 0=uint8, 1=int32, 2=float32, 3=int64. All-zero window -> 0 (safe).
    const uint4 mw = ((const uint4*)mask)[lane];
    const unsigned int anyw = mw.x | mw.y | mw.z | mw.w;
    const unsigned long long nzb = __ballot(anyw != 0u);
    const unsigned long long gt1 = __ballot((anyw & 0xFEFEFEFEu) != 0u);
    const unsigned long long m4  = __ballot((anyw & 0xFFFFFF00u) != 0u);
    const unsigned long long m84 = __ballot(((mw.y | mw.w) & 0xFFu) != 0u);
    const int flag = gt1 ? 2 : (m4 ? 0 : (m84 ? 1 : (nzb ? 3 : 0)));

    // ---- pass 1: norm partial sums (stream, hold nothing) ----
    float ssx = 0.f, ssy = 0.f, ssz = 0.f, ssw = 0.f;
    float ttx = 0.f, tty = 0.f, ttz = 0.f, ttw = 0.f;
#pragma unroll
    for (int k = 0; k < 32; ++k) {
        const int c = c0 + k;
        const float4 s4 = *reinterpret_cast<const float4*>(sp + (size_t)c * HWD);
        const float4 t4 = *reinterpret_cast<const float4*>(tp + (size_t)c * HWD);
        const float cc = center[c];                 // wave-uniform -> SGPR
        const float tx = t4.x - cc, ty = t4.y - cc, tz = t4.z - cc, tw = t4.w - cc;
        ssx = fmaf(s4.x, s4.x, ssx); ssy = fmaf(s4.y, s4.y, ssy);
        ssz = fmaf(s4.z, s4.z, ssz); ssw = fmaf(s4.w, s4.w, ssw);
        ttx = fmaf(tx, tx, ttx);     tty = fmaf(ty, ty, tty);
        ttz = fmaf(tz, tz, ttz);     ttw = fmaf(tw, tw, ttw);
    }
    *reinterpret_cast<float4*>(&red[0][wave][lane << 2]) = make_float4(ssx, ssy, ssz, ssw);
    *reinterpret_cast<float4*>(&red[1][wave][lane << 2]) = make_float4(ttx, tty, ttz, ttw);
    __syncthreads();
#pragma unroll
    for (int it = 0; it < 2; ++it) {                // 2 q x 256 px / 256 thr
        const int idx = tid + (it << 8);
        const int q = idx >> 8, p = idx & 255;
        float v = 0.f;
#pragma unroll
        for (int w = 0; w < 4; ++w) v += red[q][w][p];
        tot[q][p] = v;
    }
    __syncthreads();

    const float4 ss4 = *reinterpret_cast<const float4*>(&tot[0][lane << 2]);
    const float4 tt4 = *reinterpret_cast<const float4*>(&tot[1][lane << 2]);
    const float rsx = TAU_S_INV / fmaxf(sqrtf(ss4.x), EPSN);
    const float rsy = TAU_S_INV / fmaxf(sqrtf(ss4.y), EPSN);
    const float rsz = TAU_S_INV / fmaxf(sqrtf(ss4.z), EPSN);
    const float rsw = TAU_S_INV / fmaxf(sqrtf(ss4.w), EPSN);
    const float rtx = TAU_T_INV / fmaxf(sqrtf(tt4.x), EPSN);
    const float rty = TAU_T_INV / fmaxf(sqrtf(tt4.y), EPSN);
    const float rtz = TAU_T_INV / fmaxf(sqrtf(tt4.z), EPSN);
    const float rtw = TAU_T_INV / fmaxf(sqrtf(tt4.w), EPSN);

    // ---- pass 2: exp sums; explicit re-load of the block tile (cache-hot).
    // No max-subtraction: |bv|<=10, |av|<=25 -> exp <= 7.2e10, fp32-safe. ----
    float ebx = 0.f, eby = 0.f, ebz = 0.f, ebw = 0.f;
    float eax = 0.f, eay = 0.f, eaz = 0.f, eaw = 0.f;
    float abx = 0.f, aby = 0.f, abz = 0.f, abw = 0.f;
#pragma unroll
    for (int k = 0; k < 32; ++k) {
        const int c = c0 + k;
        const float4 s4 = *reinterpret_cast<const float4*>(sp + (size_t)c * HWD);
        const float4 t4 = *reinterpret_cast<const float4*>(tp + (size_t)c * HWD);
        const float cc = center[c];
        const float bvx = s4.x * rsx, bvy = s4.y * rsy;
        const float bvz = s4.z * rsz, bvw = s4.w * rsw;
        const float e2x = __expf((t4.x - cc) * rtx), e2y = __expf((t4.y - cc) * rty);
        const float e2z = __expf((t4.z - cc) * rtz), e2w = __expf((t4.w - cc) * rtw);
        ebx += __expf(bvx); eby += __expf(bvy); ebz += __expf(bvz); ebw += __expf(bvw);
        eax += e2x; eay += e2y; eaz += e2z; eaw += e2w;
        abx = fmaf(e2x, bvx, abx); aby = fmaf(e2y, bvy, aby);
        abz = fmaf(e2z, bvz, abz); abw = fmaf(e2w, bvw, abw);
    }
    *reinterpret_cast<float4*>(&red[0][wave][lane << 2]) = make_float4(ebx, eby, ebz, ebw);
    *reinterpret_cast<float4*>(&red[1][wave][lane << 2]) = make_float4(eax, eay, eaz, eaw);
    *reinterpret_cast<float4*>(&red[2][wave][lane << 2]) = make_float4(abx, aby, abz, abw);
    __syncthreads();
#pragma unroll
    for (int it = 0; it < 3; ++it) {                // 3 q x 256 px / 256 thr
        const int idx = tid + (it << 8);
        const int q = idx >> 8, p = idx & 255;
        float v = 0.f;
#pragma unroll
        for (int w = 0; w < 4; ++w) v += red[q][w][p];
        tot[q][p] = v;
    }
    __syncthreads();

    // ---- per-pixel loss + masked block reduction (tid = pixel) ----
    {
        const float loss = __logf(tot[0][tid]) - tot[2][tid] / tot[1][tid];
        const int gidx = b * HWD + pix0 + tid;
        bool mval;
        if (flag == 0)      mval = ((const unsigned char*)mask)[gidx] != 0;
        else if (flag == 1) mval = ((const int*)mask)[gidx] != 0;
        else if (flag == 2) mval = ((const float*)mask)[gidx] != 0.f;
        else                mval = ((const long long*)mask)[gidx] != 0;
        const bool valid = (orig_x[gidx] != 0.f) && !mval;

        float l = valid ? loss : 0.f;
        float c = valid ? 1.f  : 0.f;
        l = warp_red_sum(l);
        c = warp_red_sum(c);
        if (lane == 0) { fin[0][wave] = l; fin[1][wave] = c; }
    }
    __syncthreads();
    if (tid == 0) {
        atomicAdd(&ws[8 + b],  fin[0][0] + fin[0][1] + fin[0][2] + fin[0][3]);
        atomicAdd(&ws[16 + b], fin[1][0] + fin[1][1] + fin[1][2] + fin[1][3]);
    }
}

__global__ void finalize_kernel(const float* __restrict__ ws, float* __restrict__ out) {
    if (threadIdx.x == 0 && blockIdx.x == 0) {
        float acc = 0.f, nnz = 0.f, totc = 0.f;
#pragma unroll
        for (int i = 0; i < BB; ++i) {
            float c = ws[16 + i];
            totc += c;
            if (c > 0.f) { acc += ws[8 + i] / c; nnz += 1.f; }
        }
        out[0] = (totc > 0.f) ? acc / fmaxf(nnz, 1.f) : 0.f;
    }
}

extern "C" void kernel_launch(void* const* d_in, const int* in_sizes, int n_in,
                              void* d_out, int out_size, void* d_ws, size_t ws_size,
                              hipStream_t stream) {
    const float* s_feats = (const float*)d_in[0];
    const float* t_feats = (const float*)d_in[1];
    const float* center  = (const float*)d_in[2];
    const void*  mask    = d_in[3];
    const float* orig_x  = (const float*)d_in[4];
    float* ws = (float*)d_ws;

    hipMemsetAsync(d_ws, 0, 128, stream);
    pixel_dino_main<<<NBLK, 256, 0, stream>>>(s_feats, t_feats, center, mask,
                                              orig_x, ws);
    finalize_kernel<<<1, 64, 0, stream>>>(ws, (float*)d_out);
}